// Round 11
// baseline (430.854 us; speedup 1.0000x reference)
//
#include <hip/hip_runtime.h>
#include <hip/hip_bf16.h>
#include <math.h>

#define B_    32
#define NIN_  2312
#define NHID_ 512
#define NOUT_ 10
#define T_    350
#define KLEN  77      // truncated SRM alpha kernel length (taps 0..76)
#define MW    40      // u64 words per (b,t) input mask row (37 used, padded)
#define NIB   37      // ceil(NIN/64)
#define NTB   6       // 64-t chunks per row
#define MAXA2 320     // max active inputs per (b,t)
#define NCH   7       // t-chunks for parallel PSP IIR
#define CHL   50      // chunk length (NCH*CHL == T_)

// ---------------- W1 transpose: W1[o][i] -> W1T[i][o] ----------------
__global__ __launch_bounds__(256) void w1t_k(const float* __restrict__ W,
                                             float* __restrict__ WT) {
  __shared__ float tile[32][33];
  int i0 = blockIdx.x * 32, o0 = blockIdx.y * 32;
  int tx = threadIdx.x, tyb = threadIdx.y;
#pragma unroll
  for (int s = 0; s < 4; ++s) {
    int ty = tyb + s * 8;
    int o = o0 + ty, i = i0 + tx;
    if (i < NIN_) tile[ty][tx] = W[(size_t)o * NIN_ + i];
  }
  __syncthreads();
#pragma unroll
  for (int s = 0; s < 4; ++s) {
    int ty = tyb + s * 8;
    int i = i0 + ty, o = o0 + tx;
    if (i < NIN_) WT[(size_t)i * NHID_ + o] = tile[tx][ty];
  }
}

// ------------- input bitmask v3 (round-10 version, works) -------------
__global__ __launch_bounds__(256) void inmask_k(const float* __restrict__ X,
                                                unsigned long long* __restrict__ msk) {
  __shared__ unsigned evens[64], odds[64];
  int blk = blockIdx.x;
  int iblk = blk % NIB;
  int b = blk / NIB;
  int tid = threadIdx.x;
  int w = tid >> 6, lane = tid & 63;
  int rhalf = lane >> 5;
  int c2 = lane & 31;
  const float* base = X + ((size_t)b * NIN_ + (size_t)iblk * 64) * T_;
  for (int tb = 0; tb < NTB; ++tb) {
    int tbase = tb * 64;
#define PH1_(Q)                                                                \
  {                                                                            \
    int row = 16 * w + 2 * (Q) + rhalf;                                        \
    bool ok = (iblk * 64 + row) < NIN_ && (tbase + 2 * c2) < T_;               \
    const float* rp = base + (size_t)row * T_ + tbase + 2 * c2;                \
    float2 v = ok ? *(const float2*)rp : make_float2(0.f, 0.f);                \
    unsigned long long be = __ballot(v.x != 0.f);                              \
    unsigned long long bo = __ballot(v.y != 0.f);                              \
    if (lane == 0) {                                                           \
      evens[16 * w + 2 * (Q)] = (unsigned)be;                                  \
      odds[16 * w + 2 * (Q)] = (unsigned)bo;                                   \
    }                                                                          \
    if (lane == 1) {                                                           \
      evens[16 * w + 2 * (Q) + 1] = (unsigned)(be >> 32);                      \
      odds[16 * w + 2 * (Q) + 1] = (unsigned)(bo >> 32);                       \
    }                                                                          \
  }
    PH1_(0) PH1_(1) PH1_(2) PH1_(3) PH1_(4) PH1_(5) PH1_(6) PH1_(7)
#undef PH1_
    __syncthreads();
    unsigned ev = evens[lane], od = odds[lane];
    unsigned long long* mrow =
        msk + ((size_t)b * T_ + tbase + w * 16) * MW + iblk;
#define BAL_(P)                                                                \
  {                                                                            \
    unsigned sel = ((P) & 1) ? od : ev;                                        \
    unsigned long long bw_ =                                                   \
        __ballot(((sel >> (w * 8 + ((P) >> 1))) & 1u) != 0u);                  \
    if (lane == (P) && (tbase + w * 16 + (P)) < T_)                            \
      mrow[(size_t)(P) * MW] = bw_;                                            \
  }
    BAL_(0)  BAL_(1)  BAL_(2)  BAL_(3)  BAL_(4)  BAL_(5)  BAL_(6)  BAL_(7)
    BAL_(8)  BAL_(9)  BAL_(10) BAL_(11) BAL_(12) BAL_(13) BAL_(14) BAL_(15)
#undef BAL_
    __syncthreads();
  }
}

// ------------- sparse accumulate (round-10 version, works) -------------
__global__ __launch_bounds__(64) void accum1_k(const unsigned long long* __restrict__ msk,
                                               const float* __restrict__ WT,
                                               float* __restrict__ Z1) {
  __shared__ unsigned short list[MAXA2];
  int id = blockIdx.x;
  int bt = id >> 1, oc = id & 1;
  int lane = threadIdx.x;
  unsigned long long wm = (lane < NIB) ? msk[(size_t)bt * MW + lane] : 0ull;
  int pc = __popcll(wm);
  int pre = pc;
#pragma unroll
  for (int d = 1; d < 64; d <<= 1) {
    int o = __shfl_up(pre, d);
    if (lane >= d) pre += o;
  }
  int base = pre - pc;
  int n = __shfl(pre, 63);
  while (wm) {
    int j = __builtin_ctzll(wm);
    if (base < MAXA2) list[base] = (unsigned short)(lane * 64 + j);
    ++base;
    wm &= wm - 1;
  }
  __syncthreads();
  if (n > MAXA2) n = MAXA2;
  const float4* wbase = (const float4*)WT + (size_t)oc * 64 + lane;
  float4 acc = make_float4(0.f, 0.f, 0.f, 0.f);
#pragma unroll 16
  for (int j = 0; j < n; ++j) {
    float4 v = wbase[(size_t)list[j] * (NHID_ / 4)];
    acc.x += v.x;                       // strict ascending-i order
    acc.y += v.y;
    acc.z += v.z;
    acc.w += v.w;
  }
  ((float4*)(Z1 + (size_t)bt * NHID_))[(size_t)oc * 64 + lane] = acc;
}

// ------------- layer-1 PSP: PARALLEL chunked dual-IIR (fp64), exact -------------
// p[t] is a pure linear filter (no spike dependence), and the SRM kernel is
// truncated at 77 taps, so an IIR started from zero at s0 = max(0, t0-77)
// produces EXACT outputs for t >= t0 (telescoping cancels all older history).
// 7 chunks x 8 h-groups x 32 b = 1792 waves (7/CU) vs round-10's 256 (1/CU).
__global__ __launch_bounds__(64) void psp1_k(const float* __restrict__ Z1,
                                             float* __restrict__ P1) {
  int blk = blockIdx.x;
  int c = blk % NCH;
  int rem = blk / NCH;
  int g = rem & 7;
  int b = rem >> 3;
  int lane = threadIdx.x;
  int h = g * 64 + lane;
  const double dp  = exp(-0.1);
  const double Ap  = exp(1.0) / 10.0;
  const double D77 = exp(-7.7);
  double Xc = 0.0, Yc = 0.0, Xd = 0.0, Yd = 0.0;
  const float* zb = Z1 + (size_t)b * T_ * NHID_ + h;
  float* pb = P1 + (size_t)b * T_ * NHID_ + h;
  int t0 = c * CHL;
  int s0 = t0 - KLEN; if (s0 < 0) s0 = 0;
  int tend = t0 + CHL;
  float zc = zb[(size_t)s0 * NHID_];
  float zdc = 0.f;                      // t=s0: t-KLEN >= s0 is false
  for (int t = s0; t < tend; ++t) {
    int tn = t + 1;
    float zn  = (tn < tend) ? zb[(size_t)tn * NHID_] : 0.f;
    float zdn = (tn < tend && tn - KLEN >= s0) ? zb[(size_t)(tn - KLEN) * NHID_] : 0.f;
    Yc = dp * (Yc + Xc); Xc = dp * Xc + (double)zc;
    Yd = dp * (Yd + Xd); Xd = dp * Xd + (double)zdc;
    if (t >= t0) pb[(size_t)t * NHID_] = (float)(Ap * (Yc - D77 * (Yd + 77.0 * Xd)));
    zc = zn; zdc = zdn;
  }
}

// ------------- layer-1 refractory-only scan (cheap fp32 chain) -------------
__global__ __launch_bounds__(64) void scan1b_k(const float* __restrict__ P1,
                                               unsigned long long* __restrict__ mask) {
  int lane = threadIdx.x;
  int b = blockIdx.x >> 3, g = blockIdx.x & 7;
  int h = g * 64 + lane;
  const float Dref = (float)exp(-1.0);
  const float Cref = (float)(-20.0 * exp(1.0));
  float xr = 0.f, yr = 0.f;
  const float* pb = P1 + (size_t)b * T_ * NHID_ + h;
  unsigned long long* mb = mask + (size_t)b * T_ * 8 + g;
  for (int t0 = 0; t0 < T_; t0 += 16) {
    float p[16];
#pragma unroll
    for (int k = 0; k < 16; ++k) {
      int t = t0 + k;
      p[k] = (t < T_) ? pb[(size_t)t * NHID_] : 0.f;
    }
#pragma unroll
    for (int k = 0; k < 16; ++k) {
      int t = t0 + k;
      if (t >= T_) break;               // uniform
      yr = Dref * (yr + xr);
      float u = p[k] + Cref * yr;
      float s = (u >= 10.0f) ? 1.0f : 0.0f;
      xr = Dref * xr + s;
      unsigned long long bw = __ballot(u >= 10.0f);
      if (lane == 0) mb[(size_t)t * 8] = bw;
    }
  }
}

// ------------- layer-2 GEMM via spike bitmask -> t-major Z2T[t][320] -------------
__global__ __launch_bounds__(256) void z2_k(const unsigned long long* __restrict__ mask,
                                            const float* __restrict__ W2,
                                            float* __restrict__ Z2T) {
  int wave = blockIdx.x * 4 + (threadIdx.x >> 6);
  int lane = threadIdx.x & 63;
  if (wave >= B_ * T_) return;
  int b = wave / T_, t = wave - b * T_;
  const unsigned long long* m = mask + (size_t)wave * 8;
  if (lane < NOUT_) {
    const float* wr = W2 + (size_t)lane * NHID_;
    float acc = 0.f;
#pragma unroll
    for (int w = 0; w < 8; ++w) {
      unsigned long long mm = m[w];
      while (mm) {
        int j = __builtin_ctzll(mm);
        mm &= mm - 1;
        acc += wr[w * 64 + j];
      }
    }
    Z2T[(size_t)t * (B_ * NOUT_) + b * NOUT_ + lane] = acc;
  }
}

// ------------- layer-2 PSP: chunked dual-IIR over 320 channels -------------
__global__ __launch_bounds__(320) void psp2_k(const float* __restrict__ Z2T,
                                              float* __restrict__ P2T) {
  int n = threadIdx.x;                  // channel 0..319
  int c = blockIdx.x;
  const double dp  = exp(-0.1);
  const double Ap  = exp(1.0) / 10.0;
  const double D77 = exp(-7.7);
  double Xc = 0.0, Yc = 0.0, Xd = 0.0, Yd = 0.0;
  const float* zb = Z2T + n;
  float* pb = P2T + n;
  int t0 = c * CHL;
  int s0 = t0 - KLEN; if (s0 < 0) s0 = 0;
  int tend = t0 + CHL;
  float zc = zb[(size_t)s0 * (B_ * NOUT_)];
  float zdc = 0.f;
  for (int t = s0; t < tend; ++t) {
    int tn = t + 1;
    float zn  = (tn < tend) ? zb[(size_t)tn * (B_ * NOUT_)] : 0.f;
    float zdn = (tn < tend && tn - KLEN >= s0) ? zb[(size_t)(tn - KLEN) * (B_ * NOUT_)] : 0.f;
    Yc = dp * (Yc + Xc); Xc = dp * Xc + (double)zc;
    Yd = dp * (Yd + Xd); Xd = dp * Xd + (double)zdc;
    if (t >= t0) pb[(size_t)t * (B_ * NOUT_)] = (float)(Ap * (Yc - D77 * (Yd + 77.0 * Xd)));
    zc = zn; zdc = zdn;
  }
}

// ------------- layer-2 refractory-only scan -> output spikes -------------
__global__ __launch_bounds__(320) void scan2b_k(const float* __restrict__ P2T,
                                                float* __restrict__ out) {
  int n = threadIdx.x;                  // n = b*NOUT + o
  const float Dref = (float)exp(-1.0);
  const float Cref = (float)(-20.0 * exp(1.0));
  float xr = 0.f, yr = 0.f;
  const float* pb = P2T + n;
  float* orow = out + (size_t)n * T_;
  for (int t0 = 0; t0 < T_; t0 += 16) {
    float p[16];
#pragma unroll
    for (int k = 0; k < 16; ++k) {
      int t = t0 + k;
      p[k] = (t < T_) ? pb[(size_t)t * (B_ * NOUT_)] : 0.f;
    }
#pragma unroll
    for (int k = 0; k < 16; ++k) {
      int t = t0 + k;
      if (t >= T_) break;               // uniform
      yr = Dref * (yr + xr);
      float u = p[k] + Cref * yr;
      float s = (u >= 10.0f) ? 1.0f : 0.0f;
      xr = Dref * xr + s;
      orow[t] = s;                      // spk / Ts, Ts = 1
    }
  }
}

extern "C" void kernel_launch(void* const* d_in, const int* in_sizes, int n_in,
                              void* d_out, int out_size, void* d_ws, size_t ws_size,
                              hipStream_t stream) {
  const float* X  = (const float*)d_in[0];  // (32, 2312, 350)
  const float* W1 = (const float*)d_in[1];  // (512, 2312)
  const float* W2 = (const float*)d_in[2];  // (10, 512)
  float* out = (float*)d_out;               // (32, 10, 350)

  char* ws = (char*)d_ws;
  size_t off = 0;
  float* W1T = (float*)(ws + off);                 off += (size_t)NIN_ * NHID_ * 4;         // 4.73 MB
  unsigned long long* msk = (unsigned long long*)(ws + off); off += (size_t)B_ * T_ * MW * 8; // 3.58 MB
  float* Z1 = (float*)(ws + off);                  off += (size_t)B_ * T_ * NHID_ * 4;      // 22.9 MB
  float* P1 = (float*)(ws + off);                  off += (size_t)B_ * T_ * NHID_ * 4;      // 22.9 MB
  unsigned long long* mask = (unsigned long long*)(ws + off); off += (size_t)B_ * T_ * 8 * 8; // 0.72 MB
  float* Z2T = (float*)(ws + off);                 off += (size_t)T_ * B_ * NOUT_ * 4;      // 0.45 MB
  float* P2T = (float*)(ws + off);                 off += (size_t)T_ * B_ * NOUT_ * 4;      // 0.45 MB
  if (off > ws_size) return;  // workspace too small -> fail loudly (no launches)

  w1t_k<<<dim3((NIN_ + 31) / 32, NHID_ / 32), dim3(32, 8), 0, stream>>>(W1, W1T);
  inmask_k<<<B_ * NIB, 256, 0, stream>>>(X, msk);
  accum1_k<<<B_ * T_ * 2, 64, 0, stream>>>(msk, W1T, Z1);
  psp1_k<<<B_ * 8 * NCH, 64, 0, stream>>>(Z1, P1);
  scan1b_k<<<B_ * 8, 64, 0, stream>>>(P1, mask);
  z2_k<<<(B_ * T_ + 3) / 4, 256, 0, stream>>>(mask, W2, Z2T);
  psp2_k<<<NCH, 320, 0, stream>>>(Z2T, P2T);
  scan2b_k<<<1, 320, 0, stream>>>(P2T, out);
}

// Round 12
// 367.089 us; speedup vs baseline: 1.1737x; 1.1737x over previous
//
#include <hip/hip_runtime.h>
#include <hip/hip_bf16.h>
#include <math.h>

#define B_    32
#define NIN_  2312
#define NHID_ 512
#define NOUT_ 10
#define T_    350
#define KLEN  77      // truncated SRM alpha kernel length (taps 0..76)
#define MW    40      // u64 words per (b,t) input mask row (37 used, padded)
#define NIB   37      // ceil(NIN/64)
#define NTB   6       // 64-t chunks per row
#define MAXA2 320     // max active inputs per (b,t)
#define NCH   7       // t-chunks for parallel PSP IIR
#define CHL   50      // chunk length (NCH*CHL == T_)

// ---------------- W1 transpose: W1[o][i] -> W1T[i][o] ----------------
__global__ __launch_bounds__(256) void w1t_k(const float* __restrict__ W,
                                             float* __restrict__ WT) {
  __shared__ float tile[32][33];
  int i0 = blockIdx.x * 32, o0 = blockIdx.y * 32;
  int tx = threadIdx.x, tyb = threadIdx.y;
#pragma unroll
  for (int s = 0; s < 4; ++s) {
    int ty = tyb + s * 8;
    int o = o0 + ty, i = i0 + tx;
    if (i < NIN_) tile[ty][tx] = W[(size_t)o * NIN_ + i];
  }
  __syncthreads();
#pragma unroll
  for (int s = 0; s < 4; ++s) {
    int ty = tyb + s * 8;
    int i = i0 + ty, o = o0 + tx;
    if (i < NIN_) WT[(size_t)i * NHID_ + o] = tile[tx][ty];
  }
}

// ------------- input bitmask v3 (round-10 version, works) -------------
__global__ __launch_bounds__(256) void inmask_k(const float* __restrict__ X,
                                                unsigned long long* __restrict__ msk) {
  __shared__ unsigned evens[64], odds[64];
  int blk = blockIdx.x;
  int iblk = blk % NIB;
  int b = blk / NIB;
  int tid = threadIdx.x;
  int w = tid >> 6, lane = tid & 63;
  int rhalf = lane >> 5;
  int c2 = lane & 31;
  const float* base = X + ((size_t)b * NIN_ + (size_t)iblk * 64) * T_;
  for (int tb = 0; tb < NTB; ++tb) {
    int tbase = tb * 64;
#define PH1_(Q)                                                                \
  {                                                                            \
    int row = 16 * w + 2 * (Q) + rhalf;                                        \
    bool ok = (iblk * 64 + row) < NIN_ && (tbase + 2 * c2) < T_;               \
    const float* rp = base + (size_t)row * T_ + tbase + 2 * c2;                \
    float2 v = ok ? *(const float2*)rp : make_float2(0.f, 0.f);                \
    unsigned long long be = __ballot(v.x != 0.f);                              \
    unsigned long long bo = __ballot(v.y != 0.f);                              \
    if (lane == 0) {                                                           \
      evens[16 * w + 2 * (Q)] = (unsigned)be;                                  \
      odds[16 * w + 2 * (Q)] = (unsigned)bo;                                   \
    }                                                                          \
    if (lane == 1) {                                                           \
      evens[16 * w + 2 * (Q) + 1] = (unsigned)(be >> 32);                      \
      odds[16 * w + 2 * (Q) + 1] = (unsigned)(bo >> 32);                       \
    }                                                                          \
  }
    PH1_(0) PH1_(1) PH1_(2) PH1_(3) PH1_(4) PH1_(5) PH1_(6) PH1_(7)
#undef PH1_
    __syncthreads();
    unsigned ev = evens[lane], od = odds[lane];
    unsigned long long* mrow =
        msk + ((size_t)b * T_ + tbase + w * 16) * MW + iblk;
#define BAL_(P)                                                                \
  {                                                                            \
    unsigned sel = ((P) & 1) ? od : ev;                                        \
    unsigned long long bw_ =                                                   \
        __ballot(((sel >> (w * 8 + ((P) >> 1))) & 1u) != 0u);                  \
    if (lane == (P) && (tbase + w * 16 + (P)) < T_)                            \
      mrow[(size_t)(P) * MW] = bw_;                                            \
  }
    BAL_(0)  BAL_(1)  BAL_(2)  BAL_(3)  BAL_(4)  BAL_(5)  BAL_(6)  BAL_(7)
    BAL_(8)  BAL_(9)  BAL_(10) BAL_(11) BAL_(12) BAL_(13) BAL_(14) BAL_(15)
#undef BAL_
    __syncthreads();
  }
}

// ------------- sparse accumulate (round-10 version, works) -------------
__global__ __launch_bounds__(64) void accum1_k(const unsigned long long* __restrict__ msk,
                                               const float* __restrict__ WT,
                                               float* __restrict__ Z1) {
  __shared__ unsigned short list[MAXA2];
  int id = blockIdx.x;
  int bt = id >> 1, oc = id & 1;
  int lane = threadIdx.x;
  unsigned long long wm = (lane < NIB) ? msk[(size_t)bt * MW + lane] : 0ull;
  int pc = __popcll(wm);
  int pre = pc;
#pragma unroll
  for (int d = 1; d < 64; d <<= 1) {
    int o = __shfl_up(pre, d);
    if (lane >= d) pre += o;
  }
  int base = pre - pc;
  int n = __shfl(pre, 63);
  while (wm) {
    int j = __builtin_ctzll(wm);
    if (base < MAXA2) list[base] = (unsigned short)(lane * 64 + j);
    ++base;
    wm &= wm - 1;
  }
  __syncthreads();
  if (n > MAXA2) n = MAXA2;
  const float4* wbase = (const float4*)WT + (size_t)oc * 64 + lane;
  float4 acc = make_float4(0.f, 0.f, 0.f, 0.f);
#pragma unroll 16
  for (int j = 0; j < n; ++j) {
    float4 v = wbase[(size_t)list[j] * (NHID_ / 4)];
    acc.x += v.x;                       // strict ascending-i order
    acc.y += v.y;
    acc.z += v.z;
    acc.w += v.w;
  }
  ((float4*)(Z1 + (size_t)bt * NHID_))[(size_t)oc * 64 + lane] = acc;
}

// ------------- layer-1 PSP: PARALLEL chunked dual-IIR (fp64), exact -------------
// p[t] is a pure linear filter; kernel truncated at 77 taps, so an IIR started
// from zero at s0 = max(0, t0-77) is exact for t >= t0.
__global__ __launch_bounds__(64) void psp1_k(const float* __restrict__ Z1,
                                             float* __restrict__ P1) {
  int blk = blockIdx.x;
  int c = blk % NCH;
  int rem = blk / NCH;
  int g = rem & 7;
  int b = rem >> 3;
  int lane = threadIdx.x;
  int h = g * 64 + lane;
  const double dp  = exp(-0.1);
  const double Ap  = exp(1.0) / 10.0;
  const double D77 = exp(-7.7);
  double Xc = 0.0, Yc = 0.0, Xd = 0.0, Yd = 0.0;
  const float* zb = Z1 + (size_t)b * T_ * NHID_ + h;
  float* pb = P1 + (size_t)b * T_ * NHID_ + h;
  int t0 = c * CHL;
  int s0 = t0 - KLEN; if (s0 < 0) s0 = 0;
  int tend = t0 + CHL;
  float zc = zb[(size_t)s0 * NHID_];
  float zdc = 0.f;
  for (int t = s0; t < tend; ++t) {
    int tn = t + 1;
    float zn  = (tn < tend) ? zb[(size_t)tn * NHID_] : 0.f;
    float zdn = (tn < tend && tn - KLEN >= s0) ? zb[(size_t)(tn - KLEN) * NHID_] : 0.f;
    Yc = dp * (Yc + Xc); Xc = dp * Xc + (double)zc;
    Yd = dp * (Yd + Xd); Xd = dp * Xd + (double)zdc;
    if (t >= t0) pb[(size_t)t * NHID_] = (float)(Ap * (Yc - D77 * (Yd + 77.0 * Xd)));
    zc = zn; zdc = zdn;
  }
}

// ------------- layer-1 refractory-only scan (cheap fp32 chain) -------------
// Two fully-static unrolled inner loops, NO break (round-11 lesson: a break in
// the consumer loop blocks unroll -> p[16] demoted to scratch, 74us kernel).
// State advance past T_ is harmless (p=0 -> u<=0 -> s=0); stores predicated.
__global__ __launch_bounds__(64) void scan1b_k(const float* __restrict__ P1,
                                               unsigned long long* __restrict__ mask) {
  int lane = threadIdx.x;
  int b = blockIdx.x >> 3, g = blockIdx.x & 7;
  int h = g * 64 + lane;
  const float Dref = (float)exp(-1.0);
  const float Cref = (float)(-20.0 * exp(1.0));
  float xr = 0.f, yr = 0.f;
  const float* pb = P1 + (size_t)b * T_ * NHID_ + h;
  unsigned long long* mb = mask + (size_t)b * T_ * 8 + g;
  for (int t0 = 0; t0 < T_; t0 += 16) {
    float p[16];
#pragma unroll
    for (int k = 0; k < 16; ++k) {
      int t = t0 + k;
      p[k] = (t < T_) ? pb[(size_t)t * NHID_] : 0.f;
    }
#pragma unroll
    for (int k = 0; k < 16; ++k) {
      int t = t0 + k;
      yr = Dref * (yr + xr);
      float u = p[k] + Cref * yr;
      float s = (u >= 10.0f) ? 1.0f : 0.0f;
      xr = Dref * xr + s;
      unsigned long long bw = __ballot(u >= 10.0f);
      if (lane == 0 && t < T_) mb[(size_t)t * 8] = bw;
    }
  }
}

// ------------- layer-2 GEMM via spike bitmask -> t-major Z2T[t][320] -------------
__global__ __launch_bounds__(256) void z2_k(const unsigned long long* __restrict__ mask,
                                            const float* __restrict__ W2,
                                            float* __restrict__ Z2T) {
  int wave = blockIdx.x * 4 + (threadIdx.x >> 6);
  int lane = threadIdx.x & 63;
  if (wave >= B_ * T_) return;
  int b = wave / T_, t = wave - b * T_;
  const unsigned long long* m = mask + (size_t)wave * 8;
  if (lane < NOUT_) {
    const float* wr = W2 + (size_t)lane * NHID_;
    float acc = 0.f;
#pragma unroll
    for (int w = 0; w < 8; ++w) {
      unsigned long long mm = m[w];
      while (mm) {
        int j = __builtin_ctzll(mm);
        mm &= mm - 1;
        acc += wr[w * 64 + j];
      }
    }
    Z2T[(size_t)t * (B_ * NOUT_) + b * NOUT_ + lane] = acc;
  }
}

// ------------- layer-2 PSP: chunked dual-IIR over 320 channels -------------
__global__ __launch_bounds__(320) void psp2_k(const float* __restrict__ Z2T,
                                              float* __restrict__ P2T) {
  int n = threadIdx.x;                  // channel 0..319
  int c = blockIdx.x;
  const double dp  = exp(-0.1);
  const double Ap  = exp(1.0) / 10.0;
  const double D77 = exp(-7.7);
  double Xc = 0.0, Yc = 0.0, Xd = 0.0, Yd = 0.0;
  const float* zb = Z2T + n;
  float* pb = P2T + n;
  int t0 = c * CHL;
  int s0 = t0 - KLEN; if (s0 < 0) s0 = 0;
  int tend = t0 + CHL;
  float zc = zb[(size_t)s0 * (B_ * NOUT_)];
  float zdc = 0.f;
  for (int t = s0; t < tend; ++t) {
    int tn = t + 1;
    float zn  = (tn < tend) ? zb[(size_t)tn * (B_ * NOUT_)] : 0.f;
    float zdn = (tn < tend && tn - KLEN >= s0) ? zb[(size_t)(tn - KLEN) * (B_ * NOUT_)] : 0.f;
    Yc = dp * (Yc + Xc); Xc = dp * Xc + (double)zc;
    Yd = dp * (Yd + Xd); Xd = dp * Xd + (double)zdc;
    if (t >= t0) pb[(size_t)t * (B_ * NOUT_)] = (float)(Ap * (Yc - D77 * (Yd + 77.0 * Xd)));
    zc = zn; zdc = zdn;
  }
}

// ------------- layer-2 refractory-only scan -> output spikes -------------
// Same static-unroll/no-break fix as scan1b. 5 blocks x 64 threads (5 CUs).
__global__ __launch_bounds__(64) void scan2b_k(const float* __restrict__ P2T,
                                               float* __restrict__ out) {
  int n = blockIdx.x * 64 + threadIdx.x;    // n = b*NOUT + o
  if (n >= B_ * NOUT_) return;
  const float Dref = (float)exp(-1.0);
  const float Cref = (float)(-20.0 * exp(1.0));
  float xr = 0.f, yr = 0.f;
  const float* pb = P2T + n;
  float* orow = out + (size_t)n * T_;
  for (int t0 = 0; t0 < T_; t0 += 16) {
    float p[16];
#pragma unroll
    for (int k = 0; k < 16; ++k) {
      int t = t0 + k;
      p[k] = (t < T_) ? pb[(size_t)t * (B_ * NOUT_)] : 0.f;
    }
#pragma unroll
    for (int k = 0; k < 16; ++k) {
      int t = t0 + k;
      yr = Dref * (yr + xr);
      float u = p[k] + Cref * yr;
      float s = (u >= 10.0f) ? 1.0f : 0.0f;
      xr = Dref * xr + s;
      if (t < T_) orow[t] = s;          // spk / Ts, Ts = 1
    }
  }
}

extern "C" void kernel_launch(void* const* d_in, const int* in_sizes, int n_in,
                              void* d_out, int out_size, void* d_ws, size_t ws_size,
                              hipStream_t stream) {
  const float* X  = (const float*)d_in[0];  // (32, 2312, 350)
  const float* W1 = (const float*)d_in[1];  // (512, 2312)
  const float* W2 = (const float*)d_in[2];  // (10, 512)
  float* out = (float*)d_out;               // (32, 10, 350)

  char* ws = (char*)d_ws;
  size_t off = 0;
  float* W1T = (float*)(ws + off);                 off += (size_t)NIN_ * NHID_ * 4;         // 4.73 MB
  unsigned long long* msk = (unsigned long long*)(ws + off); off += (size_t)B_ * T_ * MW * 8; // 3.58 MB
  float* Z1 = (float*)(ws + off);                  off += (size_t)B_ * T_ * NHID_ * 4;      // 22.9 MB
  float* P1 = (float*)(ws + off);                  off += (size_t)B_ * T_ * NHID_ * 4;      // 22.9 MB
  unsigned long long* mask = (unsigned long long*)(ws + off); off += (size_t)B_ * T_ * 8 * 8; // 0.72 MB
  float* Z2T = (float*)(ws + off);                 off += (size_t)T_ * B_ * NOUT_ * 4;      // 0.45 MB
  float* P2T = (float*)(ws + off);                 off += (size_t)T_ * B_ * NOUT_ * 4;      // 0.45 MB
  if (off > ws_size) return;  // workspace too small -> fail loudly (no launches)

  w1t_k<<<dim3((NIN_ + 31) / 32, NHID_ / 32), dim3(32, 8), 0, stream>>>(W1, W1T);
  inmask_k<<<B_ * NIB, 256, 0, stream>>>(X, msk);
  accum1_k<<<B_ * T_ * 2, 64, 0, stream>>>(msk, W1T, Z1);
  psp1_k<<<B_ * 8 * NCH, 64, 0, stream>>>(Z1, P1);
  scan1b_k<<<B_ * 8, 64, 0, stream>>>(P1, mask);
  z2_k<<<(B_ * T_ + 3) / 4, 256, 0, stream>>>(mask, W2, Z2T);
  psp2_k<<<NCH, 320, 0, stream>>>(Z2T, P2T);
  scan2b_k<<<5, 64, 0, stream>>>(P2T, out);
}